// Round 2
// baseline (67.506 us; speedup 1.0000x reference)
//
#include <hip/hip_runtime.h>
#include <hip/hip_bf16.h>
#include <hip/hip_fp16.h>

#define BS   4
#define NN   2048
#define FIN  128
#define NH   4
#define FOUT 64

using f16x8 = __attribute__((ext_vector_type(8))) _Float16;
using f16x4 = __attribute__((ext_vector_type(4))) _Float16;
using f32x4 = __attribute__((ext_vector_type(4))) float;

// h16B frag-ordered layout, per (bh): [jc=j>>5][ot=o>>4][l=((j>>3)&3)*16+(o&15)][i=j&7]
// => halves offset = bh*131072 + (j>>5)*2048 + (o>>4)*512 + l*8 + i
// This is the 16x16x32 MFMA B-fragment order (n = lane&15, k = 8*(lane>>4)+i).
// Note: even if HW's true k mapping is a permutation of this, A and B share the
// same convention, so the dot product is unchanged (shared-π cancellation).

// ---------------------------------------------------------------------------
// Kernel 1: h = x @ w[h]  (fp32), fused tanh -> s_src/s_dst, h -> fp16 frag order
// grid = 16 bh * 32 row-tiles = 512 blocks, 256 threads (16x16), 4x4 thread tiles
// ---------------------------------------------------------------------------
__global__ __launch_bounds__(256) void k1_proj(
    const float* __restrict__ x, const float* __restrict__ w,
    const float* __restrict__ a_src, const float* __restrict__ a_dst,
    _Float16* __restrict__ h16B, float* __restrict__ ssrc, float* __restrict__ sdst)
{
    __shared__ __align__(16) float w_s[FIN * FOUT];   // [f][o], 32 KB
    __shared__ __align__(16) float xs[64 * 132];      // [r][f] padded, 33.8 KB

    const int t    = threadIdx.x;
    const int bx   = blockIdx.x;
    const int bh   = bx >> 5;          // 0..15
    const int tile = bx & 31;
    const int b    = bh >> 2;
    const int h    = bh & 3;
    const int n0   = tile * 64;

    // stage w[h] (8192 floats, linear)
    {
        const f32x4* wg = (const f32x4*)(w + h * FIN * FOUT);
        f32x4* wl = (f32x4*)w_s;
#pragma unroll
        for (int k = 0; k < 8; ++k) wl[t + 256 * k] = wg[t + 256 * k];
    }
    // stage x tile (64 rows x 128), row-major with pad
    {
#pragma unroll
        for (int k = 0; k < 8; ++k) {
            int q  = t + 256 * k;
            int r  = q >> 5;
            int c4 = q & 31;
            f32x4 v = *(const f32x4*)(x + (size_t)(b * NN + n0 + r) * FIN + c4 * 4);
            *(f32x4*)(xs + r * 132 + c4 * 4) = v;
        }
    }
    __syncthreads();

    const int ty = t >> 4, tx = t & 15;
    float acc[4][4] = {};

#pragma unroll 4
    for (int f4 = 0; f4 < 32; ++f4) {
        f32x4 xv[4], wv[4];
#pragma unroll
        for (int q = 0; q < 4; ++q)
            xv[q] = *(const f32x4*)(xs + (ty * 4 + q) * 132 + f4 * 4);
#pragma unroll
        for (int k = 0; k < 4; ++k)
            wv[k] = *(const f32x4*)(w_s + (f4 * 4 + k) * 64 + tx * 4);
#pragma unroll
        for (int q = 0; q < 4; ++q)
#pragma unroll
            for (int k = 0; k < 4; ++k)
#pragma unroll
                for (int c = 0; c < 4; ++c)
                    acc[q][c] += xv[q][k] * wv[k][c];
    }

    // ---- h16 scatter (frag order), packed 4 rows (contiguous i) per store ----
    const int j0 = n0 + ty * 4;   // (j0&7) in {0,4}
#pragma unroll
    for (int cc = 0; cc < 4; ++cc) {
        int o = tx * 4 + cc;
        f16x4 hv;
#pragma unroll
        for (int q = 0; q < 4; ++q) hv[q] = (_Float16)acc[q][cc];
        int off = bh * 131072 + (j0 >> 5) * 2048 + (o >> 4) * 512
                + (((j0 >> 3) & 3) * 16 + (o & 15)) * 8 + (j0 & 7);
        *(f16x4*)(h16B + off) = hv;
    }

    // ---- tanh + s_src/s_dst partials, reduce over tx (16 lanes) ----
    f32x4 a_s = *(const f32x4*)(a_src + h * FOUT + tx * 4);
    f32x4 a_d = *(const f32x4*)(a_dst + h * FOUT + tx * 4);
    float ss[4], sd[4];
#pragma unroll
    for (int q = 0; q < 4; ++q) {
        float s1 = 0.f, s2 = 0.f;
#pragma unroll
        for (int cc = 0; cc < 4; ++cc) {
            float th = tanhf(acc[q][cc]);
            s1 += th * a_s[cc];
            s2 += th * a_d[cc];
        }
        ss[q] = s1; sd[q] = s2;
    }
#pragma unroll
    for (int m = 1; m <= 8; m <<= 1) {
#pragma unroll
        for (int q = 0; q < 4; ++q) {
            ss[q] += __shfl_xor(ss[q], m);
            sd[q] += __shfl_xor(sd[q], m);
        }
    }
    if (tx == 0) {
#pragma unroll
        for (int q = 0; q < 4; ++q) {
            ssrc[bh * NN + j0 + q] = ss[q];
            sdst[bh * NN + j0 + q] = sd[q];
        }
    }
}

// ---------------------------------------------------------------------------
// Kernel 2: masked-softmax attention + PV via fp16 MFMA
// grid = 16 bh * 64 row-tiles(32 rows) = 1024 blocks, 256 threads (4 waves)
// ---------------------------------------------------------------------------
__global__ __launch_bounds__(256) void k2_attn(
    const int* __restrict__ adj,            // bool -> int32 on device
    const _Float16* __restrict__ h16B,
    const float* __restrict__ ssrc, const float* __restrict__ sdst,
    const float* __restrict__ bias, float* __restrict__ out)
{
    __shared__ __align__(16) _Float16 B_lds[2048];  // 4 KB  [ot][l][i]
    __shared__ __align__(16) _Float16 A_lds[1024];  // 2 KB  [rt][l][i]
    __shared__ float Z_lds[32];
    __shared__ float red[4];

    const int t    = threadIdx.x;
    const int wv   = t >> 6;
    const int lane = t & 63;
    const int bx   = blockIdx.x;
    const int bh   = bx >> 6;
    const int i0   = (bx & 63) * 32;
    const int b    = bh >> 2;

    // ---- D = max_j sdst[bh][j] (block-wide) ----
    float dm = -1e30f;
    {
        const float* sd = sdst + bh * NN;
#pragma unroll
        for (int k = 0; k < 8; ++k) dm = fmaxf(dm, sd[t + 256 * k]);
#pragma unroll
        for (int m = 1; m <= 32; m <<= 1) dm = fmaxf(dm, __shfl_xor(dm, m));
        if (lane == 0) red[wv] = dm;
    }
    __syncthreads();
    const float D = fmaxf(fmaxf(red[0], red[1]), fmaxf(red[2], red[3]));

    // wave wv owns local rows 8*wv..8*wv+7; lane: jl = lane&31, s = lane>>5
    const int s     = lane >> 5;
    const int jl    = lane & 31;
    const int rbase = 8 * wv + 4 * s;

    float sA[4], negC[4];
#pragma unroll
    for (int q = 0; q < 4; ++q) {
        float v = ssrc[bh * NN + i0 + rbase + q];
        sA[q] = v;
        float c = v + D;
        c = fmaxf(c, 0.2f * c);      // leaky(s_i + D) >= all row logits
        negC[q] = -c;
    }
    float zp[4] = {0.f, 0.f, 0.f, 0.f};

    const int rt  = wv >> 1;
    const int ot0 = (wv & 1) * 2;
    f32x4 acc0 = {0.f, 0.f, 0.f, 0.f};
    f32x4 acc1 = {0.f, 0.f, 0.f, 0.f};

    const _Float16* Bsrc = h16B + bh * 131072;
    const int* adjb = adj + (size_t)b * NN * NN + (size_t)(i0 + rbase) * NN;
    const float* sdrow = sdst + bh * NN;

    for (int c = 0; c < 64; ++c) {
        const int jb = c * 32;
        // stage B-tile: frag-ordered -> linear 16B per thread
        {
            uint4 v = *(const uint4*)(Bsrc + c * 2048 + t * 8);
            *(uint4*)(B_lds + t * 8) = v;
        }
        // weights for 4 rows x 1 column
        float dj = sdrow[jb + jl];
#pragma unroll
        for (int q = 0; q < 4; ++q) {
            float tt = sA[q] + dj;
            float lk = fmaxf(tt, 0.2f * tt);                 // leaky_relu(0.2)
            float e  = __expf(lk + negC[q]);                 // <= 1
            int av = adjb[(size_t)q * NN + jb + jl];
            e = av ? e : 0.f;
            zp[q] += e;
            int rq = rbase + q;
            int addr = ((rq >> 4) * 512) + (((jl >> 3) * 16 + (rq & 15)) * 8) + (jl & 7);
            A_lds[addr] = (_Float16)e;
        }
        __syncthreads();
        // PV MFMAs
        {
            f16x8 af = *(const f16x8*)(A_lds + rt * 512 + lane * 8);
            f16x8 b0 = *(const f16x8*)(B_lds + ot0 * 512 + lane * 8);
            f16x8 b1 = *(const f16x8*)(B_lds + (ot0 + 1) * 512 + lane * 8);
            acc0 = __builtin_amdgcn_mfma_f32_16x16x32_f16(af, b0, acc0, 0, 0, 0);
            acc1 = __builtin_amdgcn_mfma_f32_16x16x32_f16(af, b1, acc1, 0, 0, 0);
        }
        __syncthreads();
    }

    // ---- Z reduction over the 32 j-lanes ----
#pragma unroll
    for (int m = 1; m <= 16; m <<= 1) {
#pragma unroll
        for (int q = 0; q < 4; ++q) zp[q] += __shfl_xor(zp[q], m);
    }
    if (jl == 0) {
#pragma unroll
        for (int q = 0; q < 4; ++q) Z_lds[rbase + q] = zp[q];
    }
    __syncthreads();

    // ---- epilogue: normalize + bias, store fp32 ----
    // C/D layout (verified m89): col = lane&15, row = (lane>>4)*4 + reg
    const int n  = lane & 15;
    const int g4 = lane >> 4;
#pragma unroll
    for (int oi = 0; oi < 2; ++oi) {
        int ot = ot0 + oi;
        float bv = bias[ot * 16 + n];
        f32x4 a = (oi == 0) ? acc0 : acc1;
#pragma unroll
        for (int r = 0; r < 4; ++r) {
            int il = rt * 16 + g4 * 4 + r;
            float val = a[r] / Z_lds[il] + bv;
            out[(size_t)(bh * NN + i0 + il) * FOUT + ot * 16 + n] = val;
        }
    }
}

// ---------------------------------------------------------------------------
extern "C" void kernel_launch(void* const* d_in, const int* in_sizes, int n_in,
                              void* d_out, int out_size, void* d_ws, size_t ws_size,
                              hipStream_t stream) {
    (void)in_sizes; (void)n_in; (void)out_size; (void)ws_size;
    const float* x     = (const float*)d_in[0];
    const int*   adj   = (const int*)d_in[1];     // bool -> int32
    const float* w     = (const float*)d_in[2];
    const float* a_src = (const float*)d_in[3];
    const float* a_dst = (const float*)d_in[4];
    const float* bias  = (const float*)d_in[5];
    float*       out   = (float*)d_out;

    _Float16* h16B = (_Float16*)d_ws;                              // 4 MB
    float*    ssrc = (float*)((char*)d_ws + 4194304);              // 128 KB
    float*    sdst = (float*)((char*)d_ws + 4194304 + 131072);     // 128 KB

    k1_proj<<<512, 256, 0, stream>>>(x, w, a_src, a_dst, h16B, ssrc, sdst);
    k2_attn<<<1024, 256, 0, stream>>>(adj, h16B, ssrc, sdst, bias, out);
}

// Round 4
// 59.318 us; speedup vs baseline: 1.1380x; 1.1380x over previous
//
#include <hip/hip_runtime.h>
#include <hip/hip_fp16.h>

#define NN   2048
#define FIN  128
#define FOUT 64
#define LOG2E 1.44269504088896f

using f16x8 = __attribute__((ext_vector_type(8))) _Float16;
using f16x4 = __attribute__((ext_vector_type(4))) _Float16;
using f16x2 = __attribute__((ext_vector_type(2))) _Float16;
using f32x4 = __attribute__((ext_vector_type(4))) float;
using i32x4 = __attribute__((ext_vector_type(4))) int;

__device__ inline float fast_exp2(float x) {
#if __has_builtin(__builtin_amdgcn_exp2f)
    return __builtin_amdgcn_exp2f(x);
#else
    return exp2f(x);
#endif
}

// h16B frag-ordered layout, per (bh): halves offset =
//   bh*131072 + (j>>5)*2048 + (o>>4)*512 + (((j>>3)&3)*16 + (o&15))*8 + (j&7)
// = 16x16x32 MFMA B-fragment order (n = lane&15, k = 8*(lane>>4)+i).

// ---------------------------------------------------------------------------
// Kernel 1: h = x @ w[h] (fp32), fused tanh -> s_src/s_dst (pre-scaled by
// log2e), h -> fp16 frag order.  512 blocks x 256 threads.
// ---------------------------------------------------------------------------
__global__ __launch_bounds__(256) void k1_proj(
    const float* __restrict__ x, const float* __restrict__ w,
    const float* __restrict__ a_src, const float* __restrict__ a_dst,
    _Float16* __restrict__ h16B, float* __restrict__ ssrc, float* __restrict__ sdst)
{
    __shared__ __align__(16) float w_s[FIN * FOUT];
    __shared__ __align__(16) float xs[64 * 132];

    const int t    = threadIdx.x;
    const int bx   = blockIdx.x;
    const int bh   = bx >> 5;
    const int tile = bx & 31;
    const int b    = bh >> 2;
    const int h    = bh & 3;
    const int n0   = tile * 64;

    {
        const f32x4* wg = (const f32x4*)(w + h * FIN * FOUT);
        f32x4* wl = (f32x4*)w_s;
#pragma unroll
        for (int k = 0; k < 8; ++k) wl[t + 256 * k] = wg[t + 256 * k];
    }
    {
#pragma unroll
        for (int k = 0; k < 8; ++k) {
            int q  = t + 256 * k;
            int r  = q >> 5;
            int c4 = q & 31;
            f32x4 v = *(const f32x4*)(x + (size_t)(b * NN + n0 + r) * FIN + c4 * 4);
            *(f32x4*)(xs + r * 132 + c4 * 4) = v;
        }
    }
    __syncthreads();

    const int ty = t >> 4, tx = t & 15;
    float acc[4][4] = {};

#pragma unroll 4
    for (int f4 = 0; f4 < 32; ++f4) {
        f32x4 xv[4], wv[4];
#pragma unroll
        for (int q = 0; q < 4; ++q)
            xv[q] = *(const f32x4*)(xs + (ty * 4 + q) * 132 + f4 * 4);
#pragma unroll
        for (int k = 0; k < 4; ++k)
            wv[k] = *(const f32x4*)(w_s + (f4 * 4 + k) * 64 + tx * 4);
#pragma unroll
        for (int q = 0; q < 4; ++q)
#pragma unroll
            for (int k = 0; k < 4; ++k)
#pragma unroll
                for (int c = 0; c < 4; ++c)
                    acc[q][c] += xv[q][k] * wv[k][c];
    }

    const int j0 = n0 + ty * 4;
#pragma unroll
    for (int cc = 0; cc < 4; ++cc) {
        int o = tx * 4 + cc;
        f16x4 hv;
#pragma unroll
        for (int q = 0; q < 4; ++q) hv[q] = (_Float16)acc[q][cc];
        int off = bh * 131072 + (j0 >> 5) * 2048 + (o >> 4) * 512
                + (((j0 >> 3) & 3) * 16 + (o & 15)) * 8 + (j0 & 7);
        *(f16x4*)(h16B + off) = hv;
    }

    f32x4 a_s = *(const f32x4*)(a_src + h * FOUT + tx * 4);
    f32x4 a_d = *(const f32x4*)(a_dst + h * FOUT + tx * 4);
    float ss[4], sd[4];
#pragma unroll
    for (int q = 0; q < 4; ++q) {
        float s1 = 0.f, s2 = 0.f;
#pragma unroll
        for (int cc = 0; cc < 4; ++cc) {
            float th = tanhf(acc[q][cc]);
            s1 += th * a_s[cc];
            s2 += th * a_d[cc];
        }
        ss[q] = s1; sd[q] = s2;
    }
#pragma unroll
    for (int m = 1; m <= 8; m <<= 1) {
#pragma unroll
        for (int q = 0; q < 4; ++q) {
            ss[q] += __shfl_xor(ss[q], m);
            sd[q] += __shfl_xor(sd[q], m);
        }
    }
    if (tx == 0) {
#pragma unroll
        for (int q = 0; q < 4; ++q) {
            ssrc[bh * NN + j0 + q] = ss[q] * LOG2E;   // pre-scale: exp -> exp2
            sdst[bh * NN + j0 + q] = sd[q] * LOG2E;
        }
    }
}

// ---------------------------------------------------------------------------
// Kernel 2: barrier-light masked-softmax attention + PV (fp16 MFMA).
// 1024 blocks (16 bh x 64 row-tiles of 32), 256 threads = 4 waves.
// wave wv: rg=wv>>1 -> rows i0+rg*16+(lane&15); par=wv&1 -> chunks of that parity.
// Per iteration: stage next chunk-PAIR via global_load_lds (double-buffered,
// counted vmcnt) | per-lane e-gen in A-frag layout | 4 O-MFMAs + 1 Z-MFMA
// (ones-B) | one raw s_barrier.  End: LDS combine of parity partials.
// ---------------------------------------------------------------------------
__global__ __launch_bounds__(256, 4) void k2_attn(
    const int* __restrict__ adj,
    const _Float16* __restrict__ h16B,
    const float* __restrict__ ssrc, const float* __restrict__ sdst,
    const float* __restrict__ bias, float* __restrict__ out)
{
    __shared__ __align__(16) _Float16 Bbuf[2][4096];   // 2 x 8KB chunk-pairs
    __shared__ __align__(16) float sd_lds[NN];          // 8KB
    __shared__ __align__(16) float comb[2][64][21];     // parity-combine
    __shared__ float redmax[4];

    const int t    = threadIdx.x;
    const int wv   = t >> 6;
    const int lane = t & 63;
    const int bh   = blockIdx.x >> 6;
    const int i0   = (blockIdx.x & 63) << 5;
    const int b    = bh >> 2;
    const int rg   = wv >> 1;
    const int par  = wv & 1;
    const int m    = lane & 15;
    const int g    = lane >> 4;

    // ---- stage sdst (scaled) into LDS + block max D ----
    {
        const float* sdp = sdst + bh * NN;
        float dm = -1e30f;
#pragma unroll
        for (int k = 0; k < 8; ++k) {
            float v = sdp[t + 256 * k];
            sd_lds[t + 256 * k] = v;
            dm = fmaxf(dm, v);
        }
#pragma unroll
        for (int msk = 1; msk <= 32; msk <<= 1) dm = fmaxf(dm, __shfl_xor(dm, msk));
        if (lane == 0) redmax[wv] = dm;
    }
    __syncthreads();
    const float D = fmaxf(fmaxf(redmax[0], redmax[1]), fmaxf(redmax[2], redmax[3]));

    const int row = i0 + rg * 16 + m;
    const float sA = ssrc[bh * NN + row];
    float c = sA + D; c = fmaxf(c, 0.2f * c);          // leaky(sA+D) >= row max logit
    const float sAc  = sA - c;
    const float sAc2 = fmaf(0.2f, sA, -c);

    const int* adjrow = adj + ((size_t)b * NN + row) * NN + 8 * g;
    const _Float16* Bsrc = h16B + bh * 131072;

    f32x4 acc0 = {0,0,0,0}, acc1 = {0,0,0,0}, acc2 = {0,0,0,0}, acc3 = {0,0,0,0};
    f32x4 accz = {0,0,0,0};
    f16x8 ones;
#pragma unroll
    for (int i = 0; i < 8; ++i) ones[i] = (_Float16)1.0f;

#define STAGE(bf, p) do {                                                          \
        const _Float16* g0_ = Bsrc + (p) * 4096 + (wv * 2) * 512 + lane * 8;       \
        __builtin_amdgcn_global_load_lds(                                          \
            (const __attribute__((address_space(1))) unsigned int*)g0_,            \
            (__attribute__((address_space(3))) unsigned int*)&Bbuf[bf][(wv*2)*512],\
            16, 0, 0);                                                             \
        __builtin_amdgcn_global_load_lds(                                          \
            (const __attribute__((address_space(1))) unsigned int*)(g0_ + 512),    \
            (__attribute__((address_space(3))) unsigned int*)&Bbuf[bf][(wv*2)*512+512],\
            16, 0, 0);                                                             \
    } while (0)

    STAGE(0, 0);   // prologue: pair 0

    for (int it = 0; it < 32; ++it) {
        const int jb = (it * 2 + par) * 32;
        // adj for this lane's 8 entries (issued before stage-next => older in FIFO)
        i32x4 av0 = *(const i32x4*)(adjrow + jb);
        i32x4 av1 = *(const i32x4*)(adjrow + jb + 4);

        if (it < 31) {
            STAGE((it + 1) & 1, it + 1);
            __builtin_amdgcn_sched_barrier(0);
            asm volatile("s_waitcnt vmcnt(4)" ::: "memory");  // stage(it) done; adj+stage(it+1) may fly
            __builtin_amdgcn_sched_barrier(0);
        } else {
            __builtin_amdgcn_sched_barrier(0);
            asm volatile("s_waitcnt vmcnt(2)" ::: "memory");  // stage(31) done
            __builtin_amdgcn_sched_barrier(0);
        }

        // sdst for this lane's 8 columns
        const float* djp = sd_lds + jb + 8 * g;
        f32x4 dj0 = *(const f32x4*)(djp);
        f32x4 dj1 = *(const f32x4*)(djp + 4);

        // B fragments (linear, frag-ordered)
        const _Float16* bb = &Bbuf[it & 1][par * 2048] + lane * 8;
        f16x8 b0 = *(const f16x8*)(bb);
        f16x8 b1 = *(const f16x8*)(bb + 512);
        f16x8 b2 = *(const f16x8*)(bb + 1024);
        f16x8 b3 = *(const f16x8*)(bb + 1536);

        // e-gen directly in A-fragment layout
        float ev[8];
#pragma unroll
        for (int i = 0; i < 8; ++i) {
            float dj = (i < 4) ? dj0[i] : dj1[i - 4];
            int   av = (i < 4) ? av0[i] : av1[i - 4];
            float a1 = sAc + dj;                    // leaky(t)-C, positive branch
            float a2 = fmaf(0.2f, dj, sAc2);        // negative branch
            float ee = fast_exp2(fmaxf(a1, a2));
            ev[i] = av ? ee : 0.0f;
        }
        union { f16x8 v; f16x2 p[4]; } af;
#pragma unroll
        for (int i = 0; i < 4; ++i)
            af.p[i] = __builtin_bit_cast(f16x2,
                        __builtin_amdgcn_cvt_pkrtz(ev[2 * i], ev[2 * i + 1]));

        acc0 = __builtin_amdgcn_mfma_f32_16x16x32_f16(af.v, b0, acc0, 0, 0, 0);
        acc1 = __builtin_amdgcn_mfma_f32_16x16x32_f16(af.v, b1, acc1, 0, 0, 0);
        acc2 = __builtin_amdgcn_mfma_f32_16x16x32_f16(af.v, b2, acc2, 0, 0, 0);
        acc3 = __builtin_amdgcn_mfma_f32_16x16x32_f16(af.v, b3, acc3, 0, 0, 0);
        accz = __builtin_amdgcn_mfma_f32_16x16x32_f16(af.v, ones, accz, 0, 0, 0);

        __builtin_amdgcn_s_barrier();
    }
#undef STAGE

    // ---- combine parity partials ----
    __syncthreads();
    if (par == 1) {
        float* cp = &comb[rg][lane][0];
#pragma unroll
        for (int r = 0; r < 4; ++r) {
            cp[0 + r]  = acc0[r];
            cp[4 + r]  = acc1[r];
            cp[8 + r]  = acc2[r];
            cp[12 + r] = acc3[r];
            cp[16 + r] = accz[r];
        }
    }
    __syncthreads();
    if (par == 0) {
        const float* cp = &comb[rg][lane][0];
        float zs[4];
#pragma unroll
        for (int r = 0; r < 4; ++r) zs[r] = accz[r] + cp[16 + r];
        size_t obase = ((size_t)bh * NN + i0 + rg * 16) * FOUT;
#pragma unroll
        for (int ot = 0; ot < 4; ++ot) {
            float bv = bias[ot * 16 + m];
            f32x4 a = (ot == 0) ? acc0 : (ot == 1) ? acc1 : (ot == 2) ? acc2 : acc3;
#pragma unroll
            for (int r = 0; r < 4; ++r) {
                float v = (a[r] + cp[ot * 4 + r]) / zs[r] + bv;
                out[obase + (size_t)(g * 4 + r) * FOUT + ot * 16 + m] = v;
            }
        }
    }
}

// ---------------------------------------------------------------------------
extern "C" void kernel_launch(void* const* d_in, const int* in_sizes, int n_in,
                              void* d_out, int out_size, void* d_ws, size_t ws_size,
                              hipStream_t stream) {
    (void)in_sizes; (void)n_in; (void)out_size; (void)ws_size;
    const float* x     = (const float*)d_in[0];
    const int*   adj   = (const int*)d_in[1];     // bool -> int32
    const float* w     = (const float*)d_in[2];
    const float* a_src = (const float*)d_in[3];
    const float* a_dst = (const float*)d_in[4];
    const float* bias  = (const float*)d_in[5];
    float*       out   = (float*)d_out;

    _Float16* h16B = (_Float16*)d_ws;                              // 4 MB
    float*    ssrc = (float*)((char*)d_ws + 4194304);              // 128 KB
    float*    sdst = (float*)((char*)d_ws + 4194304 + 131072);     // 128 KB

    k1_proj<<<512, 256, 0, stream>>>(x, w, a_src, a_dst, h16B, ssrc, sdst);
    k2_attn<<<1024, 256, 0, stream>>>(adj, h16B, ssrc, sdst, bias, out);
}